// Round 7
// baseline (247.275 us; speedup 1.0000x reference)
//
#include <hip/hip_runtime.h>
#include <hip/hip_bf16.h>

using bf16 = __hip_bfloat16;
typedef __attribute__((ext_vector_type(8))) short short8;
typedef __attribute__((ext_vector_type(4))) float floatx4;

#define NB 4
#define NSEQ 4096
#define DIM 1024
#define INNER 512
#define TOK (NB * NSEQ)   // 16384

// -------------------------- memory plan (no d_ws) ---------------------------
// xbuf = x input (64 MiB): PRISTINE fp32 the whole run.
// d_out (64 MiB):
//   [0,32)   kv bf16 [16384][1024]     (stage 2 writes, stage 3 reads)
//   [32,34)  wkvb bf16 [1024][1024]    (stage 1; dead after stage 2)
//   [34,38)  M2 bf16 [4096][512]       (stage 4; dead after stage 5)
//   [38,39)  wqT bf16 [1024][512]      (stage 1; dead after stage 5)
//   [40,48)  ctx_part fp32 [16][32][64][64] (stage 3 writes, stage 4 reads)
//   [0,64)   final output              (stage 6 — reads NOTHING in d_out)
// wbuf = w_qkv input (6 MiB fp32): read only by stage 1, then dead;
//   [0,6)  W2 batches 0..2 bf16        (stage 5 writes, stage 6 reads)
// w_out buf (2 MiB fp32): pristine through stage 4, then
//   W2 batch 3 bf16 [1024][1024]       (stage 5 writes, stage 6 reads)

__device__ inline unsigned short f2bf(float x) {
  union { bf16 h; unsigned short u; } c; c.h = __float2bfloat16(x); return c.u;
}
__device__ inline float bf2f(unsigned short u) {
  return __uint_as_float((unsigned)u << 16);
}

// async global->LDS, 16 B per lane; HW writes lane i at ldsbase + i*16.
__device__ inline void gload_lds16(const bf16* g, bf16* ldsbase) {
  __builtin_amdgcn_global_load_lds(
      (const __attribute__((address_space(1))) void*)g,
      (__attribute__((address_space(3))) void*)ldsbase, 16, 0, 0);
}

#define WAITVM(N) asm volatile("s_waitcnt vmcnt(" #N ")" ::: "memory")

// ---------------------------------------------------------------------------
// Fused prep: blocks [0,512)  convert w_kv fp32 -> wkvb bf16
//             blocks [512,640) transpose wq -> wqT bf16
// (ctx zeroing removed: softmax_context now fully writes its own partials.)
// ---------------------------------------------------------------------------
__global__ __launch_bounds__(256)
void fused_prep(const float* __restrict__ w_qkv, bf16* __restrict__ wkvb,
                bf16* __restrict__ wqT) {
  const int tid = threadIdx.x;
  const int blk = blockIdx.x;

  if (blk < 512) {
    // convert w_qkv rows 512..1535 (fp32 [1024][1024]) -> bf16
    const size_t i = (size_t)blk * 256 + tid;
    const float* src = w_qkv + (size_t)INNER * DIM + i * 8;
    const float4 a = ((const float4*)src)[0];
    const float4 b = ((const float4*)src)[1];
    union { uint4 u; bf16 h[8]; } p;
    p.h[0] = __float2bfloat16(a.x); p.h[1] = __float2bfloat16(a.y);
    p.h[2] = __float2bfloat16(a.z); p.h[3] = __float2bfloat16(a.w);
    p.h[4] = __float2bfloat16(b.x); p.h[5] = __float2bfloat16(b.y);
    p.h[6] = __float2bfloat16(b.z); p.h[7] = __float2bfloat16(b.w);
    *(uint4*)(wkvb + i * 8) = p.u;
  } else {
    // wqT[c][c'] = bf16(wq[c'][c]);  wq fp32 [512][1024]
    __shared__ unsigned short t[64 * 68];
    const int q  = blk - 512;
    const int c0 = (q & 15) * 64;
    const int r0 = (q >> 4) * 64;
#pragma unroll
    for (int l = 0; l < 4; ++l) {
      const int s = l * 256 + tid;
      const int row = s >> 4, col4 = s & 15;
      const float4 v = *(const float4*)(w_qkv + (size_t)(r0 + row) * 1024 + c0 + col4 * 4);
      t[row * 68 + col4 * 4 + 0] = f2bf(v.x);
      t[row * 68 + col4 * 4 + 1] = f2bf(v.y);
      t[row * 68 + col4 * 4 + 2] = f2bf(v.z);
      t[row * 68 + col4 * 4 + 3] = f2bf(v.w);
    }
    __syncthreads();
#pragma unroll
    for (int l = 0; l < 2; ++l) {
      const int s = l * 256 + tid;
      const int cc = s >> 3, g = s & 7;
      union { uint4 u; unsigned short h[8]; } o;
#pragma unroll
      for (int u = 0; u < 8; ++u) o.h[u] = t[(g * 8 + u) * 68 + cc];
      *(uint4*)((unsigned short*)wqT + (size_t)(c0 + cc) * 512 + r0 + g * 8) = o.u;
    }
  }
}

// ---------------------------------------------------------------------------
// 128x128 GEMM (stage 5). C = A[M,K] @ W[N,K]^T. Rows >= msplit go to Calt.
// ---------------------------------------------------------------------------
template <typename TO>
__global__ __launch_bounds__(256, 4)
void gemm_bt(const bf16* __restrict__ A, int lda,
             const bf16* __restrict__ W, int mTiles,
             TO* __restrict__ C, int ldc, int K,
             TO* __restrict__ Calt, int msplit) {
  __shared__ __align__(16) bf16 As[128 * 64];
  __shared__ __align__(16) bf16 Bs[128 * 64];

  const int tid    = threadIdx.x;
  const int p      = blockIdx.x;
  const int m_tile = p % mTiles;
  const int n_tile = p / mTiles;
  const int m0     = m_tile * 128;
  const int n0     = n_tile * 128;

  const int wave = tid >> 6;
  const int lane = tid & 63;
  const int wr   = (wave >> 1) * 64;
  const int wc   = (wave & 1) * 64;
  const int quad = lane >> 4;
  const int r16  = lane & 15;
  const int rxor = r16 & 7;
  const int lrow = lane >> 3;
  const int lcol = lane & 7;
  const int gchunk = lcol ^ lrow;

  floatx4 acc[4][4];
#pragma unroll
  for (int i = 0; i < 4; ++i)
#pragma unroll
    for (int j = 0; j < 4; ++j) acc[i][j] = (floatx4)0.0f;

  const int ksteps = K >> 6;
  for (int kt = 0; kt < ksteps; ++kt) {
    const int k0 = kt << 6;
#pragma unroll
    for (int t = 0; t < 4; ++t) {
      const int s   = wave * 4 + t;
      const int row = s * 8 + lrow;
      gload_lds16(A + (size_t)(m0 + row) * lda + k0 + gchunk * 8, As + s * 512);
      gload_lds16(W + (size_t)(n0 + row) * K   + k0 + gchunk * 8, Bs + s * 512);
    }
    __syncthreads();
#pragma unroll
    for (int kk = 0; kk < 64; kk += 32) {
      const int cbase = kk >> 3;
      short8 af[4], bfg[4];
#pragma unroll
      for (int i = 0; i < 4; ++i)
        af[i] = *(const short8*)(As + (wr + i * 16 + r16) * 64 + (((quad + cbase) ^ rxor) << 3));
#pragma unroll
      for (int j = 0; j < 4; ++j)
        bfg[j] = *(const short8*)(Bs + (wc + j * 16 + r16) * 64 + (((quad + cbase) ^ rxor) << 3));
#pragma unroll
      for (int i = 0; i < 4; ++i)
#pragma unroll
        for (int j = 0; j < 4; ++j)
          acc[i][j] = __builtin_amdgcn_mfma_f32_16x16x32_bf16(af[i], bfg[j], acc[i][j], 0, 0, 0);
    }
    __syncthreads();
  }

  TO* Cb = C; int radj = 0;
  if (Calt && m0 >= msplit) { Cb = Calt; radj = msplit; }
#pragma unroll
  for (int j = 0; j < 4; ++j) {
    const int col = n0 + wc + j * 16 + r16;
#pragma unroll
    for (int i = 0; i < 4; ++i) {
      const int rowb = m0 + wr + i * 16 + quad * 4 - radj;
#pragma unroll
      for (int r = 0; r < 4; ++r)
        Cb[(size_t)(rowb + r) * ldc + col] = __float2bfloat16(acc[i][j][r]);
    }
  }
}

// ---------------------------------------------------------------------------
// 256x256 3-phase counted-vmcnt GEMM, fp32 A: C = bf16(A)[M,K] @ W[N,K]^T.
// (unchanged from R6 — see R5/R6 notes; schedule micro-opts plateaued here)
// ---------------------------------------------------------------------------
template <typename TO, bool BIAS>
__global__ __launch_bounds__(512, 1)
void gemm256f(const float* __restrict__ A,
              const bf16* __restrict__ W, size_t wbatch,
              const bf16* __restrict__ Walt,
              const float* __restrict__ bias,
              TO* __restrict__ C, int ldc, int K) {
  __shared__ __align__(16) bf16 As[2 * 16384];   // [2][256][64]
  __shared__ __align__(16) bf16 Bs[2 * 16384];

  const int tid  = threadIdx.x;
  const int p    = blockIdx.x;
  const int xcd  = p & 7, q = p >> 3;
  const int m_tile = xcd * 8 + (q & 7);   // 0..63
  const int n_tile = q >> 3;              // 0..3
  const int m0 = m_tile * 256, n0 = n_tile * 256;
  const bf16* Wp = W;
  if (wbatch) {
    const int batch = m_tile >> 4;
    Wp = (batch == 3 && Walt) ? Walt : W + (size_t)batch * wbatch;
  }

  const int wave = tid >> 6, lane = tid & 63;
  const int wm = wave >> 2, wn = wave & 3;
  const int quad = lane >> 4, r16 = lane & 15, rxor = r16 & 7;
  const int lrow = lane >> 3, lcol = lane & 7;
  const int gchunk = lcol ^ lrow;
  const int nk = K >> 6;

  const int wr8 = lane >> 3;
  const int c8  = lane & 7;
  const float* Ab = A + (size_t)(m0 + wave * 8 + wr8) * 1024 + c8 * 8;

  auto stageB = [&](int T) {
    bf16* lp = Bs + (T & 1) * 16384;
#pragma unroll
    for (int c = 0; c < 4; ++c) {
      const int rb = c * 64 + wave * 8;
      gload_lds16(Wp + (size_t)(n0 + rb + lrow) * K + T * 64 + gchunk * 8,
                  lp + rb * 64);
    }
  };
  auto loadA = [&](float4* r, int T) {
#pragma unroll
    for (int l = 0; l < 4; ++l) {
      r[2 * l]     = *(const float4*)(Ab + (size_t)l * 65536 + T * 64);
      r[2 * l + 1] = *(const float4*)(Ab + (size_t)l * 65536 + T * 64 + 4);
    }
  };
  auto writeA = [&](const float4* r, int T) {
    bf16* lp = As + (T & 1) * 16384;
#pragma unroll
    for (int l = 0; l < 4; ++l) {
      const int row = l * 64 + wave * 8 + wr8;
      union { uint4 u; unsigned short h[8]; } pk;
      pk.h[0] = f2bf(r[2*l].x);   pk.h[1] = f2bf(r[2*l].y);
      pk.h[2] = f2bf(r[2*l].z);   pk.h[3] = f2bf(r[2*l].w);
      pk.h[4] = f2bf(r[2*l+1].x); pk.h[5] = f2bf(r[2*l+1].y);
      pk.h[6] = f2bf(r[2*l+1].z); pk.h[7] = f2bf(r[2*l+1].w);
      *(uint4*)(lp + row * 64 + ((c8 ^ wr8) << 3)) = pk.u;
    }
  };

  floatx4 acc[8][4];
#pragma unroll
  for (int i = 0; i < 8; ++i)
#pragma unroll
    for (int j = 0; j < 4; ++j) acc[i][j] = (floatx4)0.0f;

  short8 a[4][2], b0[2][2], b1[2][2];

#define LDA_FRAGS(mh) do {                                                    \
  _Pragma("unroll")                                                           \
  for (int i = 0; i < 4; ++i) {                                               \
    const bf16* base = As + db * 16384 +                                      \
        (wm * 128 + (mh) * 64 + i * 16 + r16) * 64;                           \
    a[i][0] = *(const short8*)(base + ((quad ^ rxor) << 3));                  \
    a[i][1] = *(const short8*)(base + (((4 + quad) ^ rxor) << 3));            \
  } } while (0)

#define LDB_FRAGS(bt, nh) do {                                                \
  _Pragma("unroll")                                                           \
  for (int j = 0; j < 2; ++j) {                                               \
    const bf16* base = Bs + db * 16384 +                                      \
        (wn * 64 + (nh) * 32 + j * 16 + r16) * 64;                            \
    bt[j][0] = *(const short8*)(base + ((quad ^ rxor) << 3));                 \
    bt[j][1] = *(const short8*)(base + (((4 + quad) ^ rxor) << 3));           \
  } } while (0)

#define MFMA_QUAD(mh, bt, nh) do {                                            \
  _Pragma("unroll")                                                           \
  for (int i = 0; i < 4; ++i)                                                 \
  _Pragma("unroll")                                                           \
  for (int j = 0; j < 2; ++j) {                                               \
    acc[(mh)*4+i][(nh)*2+j] = __builtin_amdgcn_mfma_f32_16x16x32_bf16(        \
        a[i][0], bt[j][0], acc[(mh)*4+i][(nh)*2+j], 0, 0, 0);                 \
    acc[(mh)*4+i][(nh)*2+j] = __builtin_amdgcn_mfma_f32_16x16x32_bf16(        \
        a[i][1], bt[j][1], acc[(mh)*4+i][(nh)*2+j], 0, 0, 0);                 \
  } } while (0)

  float4 rP[8], rA[8];
  loadA(rP, 0);
  stageB(0);
  if (nk > 1) { loadA(rA, 1); WAITVM(8); }
  else        { WAITVM(0); }
  writeA(rP, 0);
  asm volatile("s_waitcnt lgkmcnt(0)" ::: "memory");
  __builtin_amdgcn_s_barrier();

  for (int T = 0; T < nk; ++T) {
    const int db = T & 1;
    // ---- P1: (mh=0, b0); stage B(T+1) into the free buffer db^1
    LDA_FRAGS(0); LDB_FRAGS(b0, 0);
    if (T + 1 < nk) stageB(T + 1);
    __builtin_amdgcn_s_barrier();
    __builtin_amdgcn_s_setprio(1);
    MFMA_QUAD(0, b0, 0);
    __builtin_amdgcn_s_setprio(0);
    __builtin_amdgcn_s_barrier();
    // ---- P2: (mh=0, b1); MFMA first, THEN retire A(T+1) + cvt + ds_write
    LDB_FRAGS(b1, 1);
    __builtin_amdgcn_s_barrier();
    __builtin_amdgcn_s_setprio(1);
    MFMA_QUAD(0, b1, 1);
    __builtin_amdgcn_s_setprio(0);
    if (T + 1 < nk) { WAITVM(4); writeA(rA, T + 1); }
    __builtin_amdgcn_s_barrier();
    // ---- P3 (merged): (mh=1, b1) + (mh=1, b0 cached); issue A(T+2) loads
    LDA_FRAGS(1);
    if (T + 2 < nk) loadA(rA, T + 2);
    __builtin_amdgcn_s_barrier();
    __builtin_amdgcn_s_setprio(1);
    MFMA_QUAD(1, b1, 1);
    MFMA_QUAD(1, b0, 0);
    __builtin_amdgcn_s_setprio(0);
    if (T + 2 < nk) WAITVM(8);   // retire B(T+1); A(T+2) stays in flight
    else            WAITVM(0);   // tail drain
    __builtin_amdgcn_s_barrier();
  }

#undef LDA_FRAGS
#undef LDB_FRAGS
#undef MFMA_QUAD

  // D mapping (verified m89/m91): row = quad*4 + reg, col = lane&15
#pragma unroll
  for (int jj = 0; jj < 4; ++jj) {
    const int col = n0 + wn * 64 + jj * 16 + r16;
    const float bv = BIAS ? bias[col] : 0.0f;
#pragma unroll
    for (int ii = 0; ii < 8; ++ii) {
      const int rowb = m0 + wm * 128 + ii * 16 + quad * 4;
#pragma unroll
      for (int r = 0; r < 4; ++r) {
        const float v = acc[ii][jj][r] + bv;
        if constexpr (sizeof(TO) == 2)
          C[(size_t)(rowb + r) * ldc + col] = __float2bfloat16(v);
        else
          C[(size_t)(rowb + r) * ldc + col] = v;
      }
    }
  }
}

// ---------------------------------------------------------------------------
// softmax(k over dh=64) + ctx_part[slice][bh][d][e] = sum_n sk[n,d]*v[n,e].
// R6 post-mortem: the old version issued 2M device-scope fp32 atomicAdds into
// a 128 KB ctx with 16-way same-address contention (16 slice-blocks per bh)
// — the inferred ~85us sink. Now each (bh,slice) block plain-stores its own
// 16 KB partial (full coverage, no zero-init, no atomics); build_m2 sums the
// 16 partials.
// ---------------------------------------------------------------------------
__global__ __launch_bounds__(256)
void softmax_context(const unsigned short* __restrict__ kv,
                     float* __restrict__ ctx_part) {
  __shared__ unsigned short skT[64 * 130];
  __shared__ unsigned short vT [64 * 130];

  const int tid   = threadIdx.x;
  const int wave  = tid >> 6;
  const int lane  = tid & 63;
  const int bh    = blockIdx.x >> 4;
  const int slice = blockIdx.x & 15;
  const int b     = bh >> 3, h = bh & 7;

  const int quad = lane >> 4;
  const int r16  = lane & 15;
  const int d0   = wave * 16;

  floatx4 acc[4];
#pragma unroll
  for (int j = 0; j < 4; ++j) acc[j] = (floatx4)0.0f;

  const int rgrp = tid >> 3;
  const int c    = tid & 7;

  for (int ch = 0; ch < 2; ++ch) {
#pragma unroll
    for (int p = 0; p < 4; ++p) {
      const int r = p * 32 + rgrp;
      const size_t rowbase =
          (size_t)(b * NSEQ + slice * 256 + ch * 128 + r) * 1024 + h * 64;
      const uint4 k8 = *(const uint4*)(kv + rowbase + c * 8);
      const uint4 v8 = *(const uint4*)(kv + rowbase + 512 + c * 8);
      const unsigned short* kb = (const unsigned short*)&k8;
      const unsigned short* vb = (const unsigned short*)&v8;

      float kf[8];
#pragma unroll
      for (int j = 0; j < 8; ++j) kf[j] = bf2f(kb[j]);
      float mx = kf[0];
#pragma unroll
      for (int j = 1; j < 8; ++j) mx = fmaxf(mx, kf[j]);
      mx = fmaxf(mx, __shfl_xor(mx, 1, 64));
      mx = fmaxf(mx, __shfl_xor(mx, 2, 64));
      mx = fmaxf(mx, __shfl_xor(mx, 4, 64));
      float e[8]; float s = 0.0f;
#pragma unroll
      for (int j = 0; j < 8; ++j) { e[j] = __expf(kf[j] - mx); s += e[j]; }
      s += __shfl_xor(s, 1, 64);
      s += __shfl_xor(s, 2, 64);
      s += __shfl_xor(s, 4, 64);
      const float inv = 1.0f / s;
#pragma unroll
      for (int j = 0; j < 8; ++j) {
        const int d = c * 8 + j;
        skT[d * 130 + r] = f2bf(e[j] * inv);
        vT [d * 130 + r] = vb[j];
      }
    }
    __syncthreads();

#pragma unroll
    for (int kk = 0; kk < 4; ++kk) {
      const int kof = kk * 32 + quad * 8;
      union { short8 v; unsigned u[4]; } afr;
      {
        const unsigned* q = (const unsigned*)(skT + (d0 + r16) * 130 + kof);
        afr.u[0] = q[0]; afr.u[1] = q[1]; afr.u[2] = q[2]; afr.u[3] = q[3];
      }
#pragma unroll
      for (int j = 0; j < 4; ++j) {
        union { short8 v; unsigned u[4]; } bfr;
        const unsigned* q = (const unsigned*)(vT + (j * 16 + r16) * 130 + kof);
        bfr.u[0] = q[0]; bfr.u[1] = q[1]; bfr.u[2] = q[2]; bfr.u[3] = q[3];
        acc[j] = __builtin_amdgcn_mfma_f32_16x16x32_bf16(afr.v, bfr.v, acc[j], 0, 0, 0);
      }
    }
    __syncthreads();
  }

  // Plain stores to this block's private partial (full 64x64 coverage).
  float* cg = ctx_part + ((size_t)slice * 32 + bh) * 4096;
#pragma unroll
  for (int j = 0; j < 4; ++j) {
    const int e = j * 16 + r16;
#pragma unroll
    for (int r = 0; r < 4; ++r) {
      const int d = d0 + quad * 4 + r;
      cg[d * 64 + e] = acc[j][r];
    }
  }
}

// ---------------------------------------------------------------------------
// M2[b*1024+o][h*64+d] = sum_e w_out[o][h*64+e] * ctx[b,h][d][e]; w_out fp32.
// ctx[bh] = sum over 16 slice-partials (summed during LDS staging).
// ---------------------------------------------------------------------------
__global__ __launch_bounds__(256)
void build_m2(const float* __restrict__ w_out, const float* __restrict__ ctx_part,
              bf16* __restrict__ M2) {
  __shared__ unsigned short wo_s[128 * 68];
  __shared__ __align__(16) float ctx_s[4096];

  const int tid = threadIdx.x;
  const int bh  = blockIdx.y;
  const int b   = bh >> 3, h = bh & 7;
  const int o0  = blockIdx.x * 128;

#pragma unroll
  for (int l = 0; l < 8; ++l) {
    const int s = l * 256 + tid;
    const int row = s >> 4, col4 = s & 15;
    const float4 v = *(const float4*)(w_out + (size_t)(o0 + row) * 512 + h * 64 + col4 * 4);
    wo_s[row * 68 + col4 * 4 + 0] = f2bf(v.x);
    wo_s[row * 68 + col4 * 4 + 1] = f2bf(v.y);
    wo_s[row * 68 + col4 * 4 + 2] = f2bf(v.z);
    wo_s[row * 68 + col4 * 4 + 3] = f2bf(v.w);
  }
  // ctx_s = sum over 16 slice partials (slice stride = 32*4096 fp32 = 32768 f4)
  const float4* cg = (const float4*)(ctx_part + (size_t)bh * 4096);
#pragma unroll
  for (int l = 0; l < 4; ++l) {
    const int idx = l * 256 + tid;
    float4 s = make_float4(0.f, 0.f, 0.f, 0.f);
#pragma unroll
    for (int sl = 0; sl < 16; ++sl) {
      const float4 v = cg[(size_t)sl * 32768 + idx];
      s.x += v.x; s.y += v.y; s.z += v.z; s.w += v.w;
    }
    ((float4*)ctx_s)[idx] = s;
  }
  __syncthreads();

  const int o_loc = tid & 127;
  const int dbase = (tid >> 7) * 32;
  float acc[32];
#pragma unroll
  for (int d = 0; d < 32; ++d) acc[d] = 0.0f;

  for (int e = 0; e < 64; ++e) {
    const float wf = bf2f(wo_s[o_loc * 68 + e]);
#pragma unroll
    for (int d = 0; d < 32; ++d)
      acc[d] += wf * ctx_s[(dbase + d) * 64 + e];
  }

  union { uint4 u[4]; unsigned short h[32]; } o;
#pragma unroll
  for (int d = 0; d < 32; ++d) o.h[d] = f2bf(acc[d]);
  unsigned short* dst = (unsigned short*)M2 + (size_t)(b * 1024 + o0 + o_loc) * 512 + h * 64 + dbase;
#pragma unroll
  for (int i = 0; i < 4; ++i) ((uint4*)dst)[i] = o.u[i];
}

// ---------------------------------------------------------------------------
extern "C" void kernel_launch(void* const* d_in, const int* in_sizes, int n_in,
                              void* d_out, int out_size, void* d_ws, size_t ws_size,
                              hipStream_t stream) {
  const float* x     = (const float*)d_in[0];
  const float* w_qkv = (const float*)d_in[1];
  const float* w_out = (const float*)d_in[2];
  const float* b_out = (const float*)d_in[3];
  float* out = (float*)d_out;

  char* wbuf = (char*)d_in[1];
  char* obuf = (char*)d_out;

  bf16*  kv   = (bf16*)obuf;                         // d_out[0,32)
  bf16*  wkvb = (bf16*)(obuf + (size_t)33554432);    // d_out[32,34)
  bf16*  M2   = (bf16*)(obuf + (size_t)35651584);    // d_out[34,38)
  bf16*  wqT  = (bf16*)(obuf + (size_t)39845888);    // d_out[38,39)
  float* ctxp = (float*)(obuf + (size_t)41943040);   // d_out[40,48): partials
  bf16*  W2   = (bf16*)wbuf;                         // wbuf[0,6): batches 0-2
  bf16*  W2b3 = (bf16*)d_in[2];                      // w_out buf: batch 3

  // 1) fused prep: wkvb convert + wqT transpose
  fused_prep<<<640, 256, 0, stream>>>(w_qkv, wkvb, wqT);

  // 2) kv = bf16(x) @ wkvb^T -> d_out[0,32). fp32-A 256x256 tiles.
  gemm256f<bf16, false><<<256, 512, 0, stream>>>(
      x, wkvb, 0, nullptr, nullptr, kv, 1024, DIM);

  // 3) ctx partials = softmax(k)^T v  (no atomics; 16 partials per bh)
  softmax_context<<<512, 256, 0, stream>>>((const unsigned short*)kv, ctxp);

  // 4) M2 = w_out folded through summed ctx -> d_out[34,38)
  build_m2<<<dim3(8, 32), 256, 0, stream>>>(w_out, ctxp, M2);

  // 5) W2 = M2 @ wqT^T; rows<3072 -> wbuf[0,6), rows>=3072 -> w_out buf.
  gemm_bt<bf16><<<256, 256, 0, stream>>>(
      M2, 512, wqT, 32, W2, 1024, 512, W2b3, 3072);

  // 6) out = bf16(x) @ W2[b]^T + b_out -> d_out (reads nothing in d_out).
  gemm256f<float, true><<<256, 512, 0, stream>>>(
      x, W2, (size_t)1048576, W2b3, b_out, out, DIM, DIM);
}